// Round 1
// 286.609 us; speedup vs baseline: 1.0106x; 1.0106x over previous
//
#include <hip/hip_runtime.h>
#include <hip/hip_bf16.h>
#include <hip/hip_fp16.h>
#include <type_traits>

// ---- problem constants ----
#define B_    2
#define LQ_   21760
#define LEN_  21760
#define DM    256
#define NH    8
#define NL    4
#define NP    4
#define HD    32

// workspace layout (bytes)
#define WS_VAL   0u            // f16 value [B][H][21760][32]      22,282,240
#define WS_SAMP  22282240u     // bf16 sampled [B*LQ][256]         22,282,240
#define WS_OA    44564480u     // f16 off|attn [B*LQ][384]         33,423,360
#define WS_WT    77987840u     // bf16 W^T arena: val|oa|out        458,752

typedef __attribute__((ext_vector_type(4))) float f32x4;
typedef __attribute__((ext_vector_type(8))) short bf16x8;
typedef __attribute__((ext_vector_type(4))) unsigned int u32x4;
typedef __attribute__((ext_vector_type(2))) unsigned int u32x2;

__device__ __forceinline__ unsigned short f2bf(float v) {
    __hip_bfloat16 h = __float2bfloat16(v);
    return *reinterpret_cast<unsigned short*>(&h);
}
__device__ __forceinline__ unsigned int pk2bf(float a, float b) {
    return (unsigned int)f2bf(a) | ((unsigned int)f2bf(b) << 16);
}
__device__ __forceinline__ unsigned int pk2h(float a, float b) {
    __half2 h = __floats2half2_rn(a, b);
    union { __half2 h; unsigned int u; } c; c.h = h; return c.u;
}
__device__ __forceinline__ __half2 u2h2(unsigned int u) {
    union { unsigned int u; __half2 h; } c; c.u = u; return c.h;
}

// ---------------------------------------------------------------------------
// All four weight transposes in one dispatch. W[K=256,N] f32 -> Wt[N,256] bf16.
// ---------------------------------------------------------------------------
__global__ __launch_bounds__(256) void wt_cvt_all(const float* __restrict__ Wv,
                                                  const float* __restrict__ Wo,
                                                  const float* __restrict__ Wa,
                                                  const float* __restrict__ Wu,
                                                  unsigned short* __restrict__ wt) {
    const float* Ws[4] = {Wv, Wo, Wa, Wu};
    const int Ns[4] = {256, 256, 128, 256};
    const unsigned int dof[4] = {0u, 65536u, 131072u, 163840u};
    const int m = blockIdx.z;
    const int n0 = blockIdx.x * 16, k0 = blockIdx.y * 16;
    if (n0 >= Ns[m]) return;
    __shared__ float tile[16][17];
    const int tx = threadIdx.x & 15, ty = threadIdx.x >> 4;
    tile[ty][tx] = Ws[m][(size_t)(k0 + ty) * Ns[m] + n0 + tx];
    __syncthreads();
    wt[dof[m] + (size_t)(n0 + ty) * 256 + k0 + tx] = f2bf(tile[tx][ty]);
}

// ---------------------------------------------------------------------------
// Merged pre-GEMMs (one dispatch, 2 jobs):
//  job0 (x=0..1): value = inpf @ Wt_val + b_val -> f16, PERMUTED [b][h][pix][32]
//  job1 (x=2..4): oa    = query @ Wt_oa + (b_off|b_attn) -> f16 flat [bq][384]
// 128x128 tile, BK=32, 4 waves. A is f32, converted to bf16 during staging.
// grid (5, 340).
// ---------------------------------------------------------------------------
__global__ __launch_bounds__(256) void gemm_pre(const float* __restrict__ inpf,
                                                const float* __restrict__ query,
                                                const unsigned short* __restrict__ Wt_val,
                                                const unsigned short* __restrict__ Wt_oa,
                                                const float* __restrict__ b_val,
                                                const float* __restrict__ b_off,
                                                const float* __restrict__ b_attn,
                                                unsigned short* __restrict__ val_h,
                                                unsigned short* __restrict__ oa_h) {
    __shared__ unsigned short As[128 * 32];
    __shared__ unsigned short Bs[128 * 32];
    const int t = threadIdx.x;
    const int wv = t >> 6;
    const int ln = t & 63;
    const int job = (blockIdx.x >= 2);
    const int n0 = (job ? (blockIdx.x - 2) : blockIdx.x) * 128;
    const int m0 = blockIdx.y * 128;
    const float* A = job ? query : inpf;
    const unsigned short* Bt = job ? Wt_oa : Wt_val;
    const int K = 256;
    const int wm = (wv & 1) * 64;
    const int wn = (wv >> 1) * 64;
    const int lrow = ln & 15;
    const int kq = ln >> 4;

    f32x4 acc[4][4] = {};

    for (int k0 = 0; k0 < K; k0 += 32) {
#pragma unroll
        for (int c = 0; c < 4; ++c) {
            const int i = t + c * 256;
            const int row = i >> 3;
            const int kq4 = (i & 7) * 4;
            f32x4 v = *(const f32x4*)&A[(size_t)(m0 + row) * K + k0 + kq4];
            uint2 p = make_uint2(pk2bf(v.x, v.y), pk2bf(v.z, v.w));
            *(uint2*)((char*)As + row * 64 + kq4 * 2) = p;
        }
#pragma unroll
        for (int c = 0; c < 2; ++c) {
            const int o = c * 4096 + t * 16;
            const int row = o >> 6;
            const int ke = (o & 63) >> 1;
            const unsigned short* gb = Bt + (size_t)(n0 + row) * K + k0 + ke;
            __builtin_amdgcn_global_load_lds(
                (const __attribute__((address_space(1))) void*)gb,
                (__attribute__((address_space(3))) void*)((char*)Bs + o), 16, 0, 0);
        }
        __syncthreads();

        bf16x8 af[4], bfr[4];
#pragma unroll
        for (int i = 0; i < 4; ++i) {
            af[i]  = *(const bf16x8*)((char*)As + (wm + i * 16 + lrow) * 64 + kq * 16);
            bfr[i] = *(const bf16x8*)((char*)Bs + (wn + i * 16 + lrow) * 64 + kq * 16);
        }
#pragma unroll
        for (int i = 0; i < 4; ++i)
#pragma unroll
            for (int j = 0; j < 4; ++j)
                acc[i][j] = __builtin_amdgcn_mfma_f32_16x16x32_bf16(af[i], bfr[j], acc[i][j], 0, 0, 0);
        __syncthreads();
    }

    // epilogue: C/D mapping col = lane&15, row = (lane>>4)*4 + reg
    const int b = m0 / LQ_;       // block never straddles batch (21760 % 128 == 0)
#pragma unroll
    for (int j = 0; j < 4; ++j) {
        const int n = n0 + wn + j * 16 + lrow;
        const float bb = job ? ((n < 256) ? b_off[n] : b_attn[n - 256]) : b_val[n];
#pragma unroll
        for (int i = 0; i < 4; ++i) {
            const int mrow = m0 + wm + i * 16 + kq * 4;
#pragma unroll
            for (int r = 0; r < 4; ++r) {
                const float v = acc[i][j][r] + bb;
                const unsigned short hv = (unsigned short)__half_as_ushort(__float2half(v));
                if (job) {
                    oa_h[(size_t)(mrow + r) * 384 + n] = hv;
                } else {
                    const int pix = (mrow + r) - b * LQ_;
                    const int h = n >> 5, c = n & 31;
                    val_h[((size_t)(b * NH + h) * LQ_ + pix) * HD + c] = hv;
                }
            }
        }
    }
}

// ---------------------------------------------------------------------------
// out = sampled(bf16) @ Wt_out + b_out -> f32. grid (2, 340) (x = n for LLC
// locality of the shared A-tile).
// ---------------------------------------------------------------------------
__global__ __launch_bounds__(256) void gemm_out(const unsigned short* __restrict__ Ab,
                                                const unsigned short* __restrict__ Bt,
                                                const float* __restrict__ bias,
                                                float* __restrict__ C) {
    __shared__ unsigned short As[128 * 32];
    __shared__ unsigned short Bs[128 * 32];
    const int t = threadIdx.x;
    const int wv = t >> 6;
    const int ln = t & 63;
    const int n0 = blockIdx.x * 128;
    const int m0 = blockIdx.y * 128;
    const int N = 256, K = 256;
    const int wm = (wv & 1) * 64;
    const int wn = (wv >> 1) * 64;
    const int lrow = ln & 15;
    const int kq = ln >> 4;

    f32x4 acc[4][4] = {};

    for (int k0 = 0; k0 < K; k0 += 32) {
#pragma unroll
        for (int c = 0; c < 2; ++c) {
            const int o = c * 4096 + t * 16;
            const int row = o >> 6;
            const int ke = (o & 63) >> 1;
            const unsigned short* ga = Ab + (size_t)(m0 + row) * K + k0 + ke;
            const unsigned short* gb = Bt + (size_t)(n0 + row) * K + k0 + ke;
            __builtin_amdgcn_global_load_lds(
                (const __attribute__((address_space(1))) void*)ga,
                (__attribute__((address_space(3))) void*)((char*)As + o), 16, 0, 0);
            __builtin_amdgcn_global_load_lds(
                (const __attribute__((address_space(1))) void*)gb,
                (__attribute__((address_space(3))) void*)((char*)Bs + o), 16, 0, 0);
        }
        __syncthreads();

        bf16x8 af[4], bfr[4];
#pragma unroll
        for (int i = 0; i < 4; ++i) {
            af[i]  = *(const bf16x8*)((char*)As + (wm + i * 16 + lrow) * 64 + kq * 16);
            bfr[i] = *(const bf16x8*)((char*)Bs + (wn + i * 16 + lrow) * 64 + kq * 16);
        }
#pragma unroll
        for (int i = 0; i < 4; ++i)
#pragma unroll
            for (int j = 0; j < 4; ++j)
                acc[i][j] = __builtin_amdgcn_mfma_f32_16x16x32_bf16(af[i], bfr[j], acc[i][j], 0, 0, 0);
        __syncthreads();
    }

#pragma unroll
    for (int j = 0; j < 4; ++j) {
        const int n = n0 + wn + j * 16 + lrow;
        const float bb = bias[n];
#pragma unroll
        for (int i = 0; i < 4; ++i) {
            const int mrow = m0 + wm + i * 16 + kq * 4;
#pragma unroll
            for (int r = 0; r < 4; ++r)
                C[(size_t)(mrow + r) * N + n] = acc[i][j][r] + bb;
        }
    }
}

// ---------------------------------------------------------------------------
// Deformable sampling v6: HEAD-partitioned across XCDs.
//   grid = 10880 blocks; j&7 = head (-> XCD under round-robin dispatch),
//   j>>3 = (b, 32-query chunk). Per-XCD value working set = B*1head*21760*64B
//   = 2.72 MB < 4 MB L2 -> value gathers become L2-resident.
// Block = 32 queries x 1 head. Wave = 8 queries x 8 dg lanes.
// Inner accumulate uses packed fp16 FMA (v_pk_fma_f16) with f32 flush every
// 4 lp; weight lane-broadcast via one v_perm_b32 (per-lane const selector).
// 1-deep software prefetch of LDS entry + both value rows.
// LDS entry addressing XOR-swizzled: word = (q*64 + ql*4) ^ (lp*4)
// (bits disjoint -> == q*64 + ((lp^ql)<<2)), conflict-free b128 reads.
// ---------------------------------------------------------------------------
#define QB6 32
__global__ __launch_bounds__(256) void msda_sample6(const unsigned short* __restrict__ value,
                                                    const unsigned short* __restrict__ oa,
                                                    const float* __restrict__ refp,
                                                    unsigned short* __restrict__ samp) {
    __shared__ __align__(16) char smem[9216];
    unsigned int* s_pkw = (unsigned int*)smem;            // 8 KB (phase B), aliases below
    float* s_off   = (float*)smem;                        // 32q * 32 f32 = 4 KB
    float* s_logit = (float*)(smem + 4096);               // 32q * 16 f32 = 2 KB
    float* s_aw    = (float*)(smem + 6144);               // 32q * 16 f32 = 2 KB
    float* s_ref   = (float*)(smem + 8192);               // 32q * 8 f32 = 1 KB (non-aliased)

    const int t = threadIdx.x;
    const int j = blockIdx.x;                 // 10880 blocks
    const int h = j & 7;                      // head, pinned per XCD
    const int bqc = j >> 3;                   // 0..1359
    const int b = (bqc >= 680);
    const int q0 = (bqc - b * 680) * QB6;     // batch-local query base
    const int bq0 = b * LQ_ + q0;             // global row base

    // phase 0: stage this head's oa slice (f16 -> f32) + refs, nontemporal.
    // t = q(5b) * 8 + c(3b)
    {
        const int q = t >> 3, c = t & 7;
        const unsigned short* oab = oa + (size_t)(bq0 + q) * 384;
        // 32 offsets (64 B slice at h*32, 8 B per lane)
        u32x2 r0 = __builtin_nontemporal_load((const u32x2*)(oab + h * 32) + c);
        float2 f0 = __half22float2(u2h2(r0.x));
        float2 f1 = __half22float2(u2h2(r0.y));
        f32x4 o0 = {f0.x, f0.y, f1.x, f1.y};
        ((f32x4*)s_off)[q * 8 + c] = o0;
        // 16 logits (32 B slice at 256 + h*16, 4 B per lane)
        unsigned int r1 = __builtin_nontemporal_load((const unsigned int*)(oab + 256 + h * 16) + c);
        float2 g0 = __half22float2(u2h2(r1));
        ((float2*)s_logit)[q * 8 + c] = make_float2(g0.x, g0.y);
        // 8 refs per q (32 B, 4 B per lane)
        s_ref[q * 8 + c] = __builtin_nontemporal_load(refp + (size_t)(bq0 + q) * 8 + c);
    }
    __syncthreads();

    // phase A1: 32 softmaxes (one per query, this head) over 16 logits
    if (t < 32) {
        const float* lg = s_logit + t * 16;
        float m = -1e30f;
#pragma unroll
        for (int i = 0; i < 16; ++i) m = fmaxf(m, lg[i]);
        float e[16], s = 0.f;
#pragma unroll
        for (int i = 0; i < 16; ++i) { e[i] = __expf(lg[i] - m); s += e[i]; }
        const float inv = 1.f / s;
#pragma unroll
        for (int i = 0; i < 16; ++i) s_aw[t * 16 + i] = e[i] * inv;
    }
    __syncthreads();

    // phase A2: 2 samples/thread -> registers. s = q(5b)*16 + lp(4b)
    uint4 ent[2];
    int wrd[2];
    {
        const int Wls[4] = {128, 64, 32, 16};
        const int Hls[4] = {128, 64, 32, 16};
        const int st_[4] = {0, 16384, 20480, 21504};
#pragma unroll
        for (int ii = 0; ii < 2; ++ii) {
            const int s = t * 2 + ii;
            const int q = s >> 4;
            const int lp = s & 15;
            const int l = lp >> 2;
            const int Wl = Wls[l], Hl = Hls[l], base = st_[l];
            const float ix = s_ref[q * 8 + l * 2]     * (float)Wl - 0.5f + s_off[q * 32 + lp * 2];
            const float iy = s_ref[q * 8 + l * 2 + 1] * (float)Hl - 0.5f + s_off[q * 32 + lp * 2 + 1];
            const float fix = floorf(ix), fiy = floorf(iy);
            const int x0 = (int)fix, y0 = (int)fiy;
            const float fx = ix - fix, fy = iy - fiy;
            // x-pair: start sx in [0, Wl-2]; (wl, wr) = weights of pixels sx, sx+1
            int sx; float wl, wr;
            if (x0 < 0)            { sx = 0;      wl = (x0 == -1) ? fx : 0.f;        wr = 0.f; }
            else if (x0 >= Wl - 1) { sx = Wl - 2; wl = 0.f; wr = (x0 == Wl - 1) ? (1.f - fx) : 0.f; }
            else                   { sx = x0;     wl = 1.f - fx;                     wr = fx; }
            // y rows
            const float g0 = ((y0 >= 0) & (y0 < Hl)) ? (1.f - fy) : 0.f;
            const float g1 = ((y0 + 1 >= 0) & (y0 + 1 < Hl)) ? fy : 0.f;
            const int cy0 = min(max(y0, 0), Hl - 1);
            const int cy1 = min(max(y0 + 1, 0), Hl - 1);
            const float aw = s_aw[q * 16 + lp];
            ent[ii].x = (unsigned int)(base + cy0 * Wl + sx);
            ent[ii].y = (unsigned int)(base + cy1 * Wl + sx);
            ent[ii].z = pk2h(aw * wl * g0, aw * wr * g0);
            ent[ii].w = pk2h(aw * wl * g1, aw * wr * g1);
            wrd[ii] = q * 64 + ((lp ^ (q & 7)) << 2);
        }
    }
    __syncthreads();  // phase-A reads done; safe to overwrite aliased region

#pragma unroll
    for (int ii = 0; ii < 2; ++ii)
        *(uint4*)&s_pkw[wrd[ii]] = ent[ii];
    __syncthreads();

    // phase B: wave = 8 queries x 8 dg; lane's pixel = sx + (dg>=4), ch = (dg&3)*8..
    const int lane = t & 63;
    const int wv = t >> 6;
    const int ql = lane >> 3;                 // 0..7 within wave
    const int q = wv * 8 + ql;                // block-local query 0..31
    const int dg = lane & 7;
    const unsigned short* vb = value + ((size_t)(b * NH + h) * LQ_) * HD + dg * 8;
    const unsigned int wsel = (dg < 4) ? 0x01000100u : 0x03020302u;  // v_perm: replicate lo/hi half
    const int wb = q * 64 + (ql << 2);        // swizzled entry base (bits disjoint from lp<<2)

    float facc[8] = {0.f, 0.f, 0.f, 0.f, 0.f, 0.f, 0.f, 0.f};
    __half2 ah[4] = {u2h2(0u), u2h2(0u), u2h2(0u), u2h2(0u)};

    uint4 pk = *(const uint4*)&s_pkw[wb];     // lp = 0
    uint4 va0 = *(const uint4*)(vb + (size_t)pk.x * HD);
    uint4 va1 = *(const uint4*)(vb + (size_t)pk.y * HD);
    unsigned int wz = pk.z, ww = pk.w;

#pragma unroll
    for (int lp = 0; lp < 16; ++lp) {
        const uint4 cv0 = va0, cv1 = va1;
        const unsigned int cz = wz, cw = ww;
        if (lp < 15) {
            uint4 pn = *(const uint4*)&s_pkw[wb ^ ((lp + 1) << 2)];
            wz = pn.z; ww = pn.w;
            va0 = *(const uint4*)(vb + (size_t)pn.x * HD);
            va1 = *(const uint4*)(vb + (size_t)pn.y * HD);
        }
        const __half2 w0 = u2h2(__builtin_amdgcn_perm(cz, cz, wsel));
        const __half2 w1 = u2h2(__builtin_amdgcn_perm(cw, cw, wsel));
#pragma unroll
        for (int c2 = 0; c2 < 4; ++c2) {
            ah[c2] = __hfma2(w0, u2h2((&cv0.x)[c2]), ah[c2]);
            ah[c2] = __hfma2(w1, u2h2((&cv1.x)[c2]), ah[c2]);
        }
        if ((lp & 3) == 3) {   // flush fp16 partials to f32 every 4 lp
#pragma unroll
            for (int c2 = 0; c2 < 4; ++c2) {
                float2 f = __half22float2(ah[c2]);
                facc[c2 * 2]     += f.x;
                facc[c2 * 2 + 1] += f.y;
                ah[c2] = u2h2(0u);
            }
        }
    }

    // combine left-pixel (dg<4) and right-pixel (dg>=4) partials
#pragma unroll
    for (int i = 0; i < 8; ++i) facc[i] += __shfl_xor(facc[i], 4);

    if (dg < 4) {
        u32x4 o;
        o.x = pk2bf(facc[0], facc[1]);
        o.y = pk2bf(facc[2], facc[3]);
        o.z = pk2bf(facc[4], facc[5]);
        o.w = pk2bf(facc[6], facc[7]);
        __builtin_nontemporal_store(o, (u32x4*)(samp + (size_t)(bq0 + q) * 256 + h * HD + dg * 8));
    }
}

extern "C" void kernel_launch(void* const* d_in, const int* in_sizes, int n_in,
                              void* d_out, int out_size, void* d_ws, size_t ws_size,
                              hipStream_t stream) {
    const float* query  = (const float*)d_in[0];
    const float* refp   = (const float*)d_in[1];
    const float* inpf   = (const float*)d_in[2];
    const float* W_off  = (const float*)d_in[3];
    const float* b_off  = (const float*)d_in[4];
    const float* W_attn = (const float*)d_in[5];
    const float* b_attn = (const float*)d_in[6];
    const float* W_val  = (const float*)d_in[7];
    const float* b_val  = (const float*)d_in[8];
    const float* W_out  = (const float*)d_in[9];
    const float* b_out  = (const float*)d_in[10];
    float* out = (float*)d_out;

    char* ws = (char*)d_ws;
    unsigned short* val_h   = (unsigned short*)(ws + WS_VAL);
    unsigned short* samp_bf = (unsigned short*)(ws + WS_SAMP);
    unsigned short* oa_h    = (unsigned short*)(ws + WS_OA);
    unsigned short* wt      = (unsigned short*)(ws + WS_WT);
    unsigned short* Wt_val  = wt;
    unsigned short* Wt_oa   = wt + 65536;
    unsigned short* Wt_out  = wt + 163840;

    const int M = B_ * LQ_;          // 43520

    wt_cvt_all<<<dim3(16, 16, 4), 256, 0, stream>>>(W_val, W_off, W_attn, W_out, wt);

    // merged value + off/attn GEMMs
    gemm_pre<<<dim3(5, M / 128), 256, 0, stream>>>(
        inpf, query, Wt_val, Wt_oa, b_val, b_off, b_attn, val_h, oa_h);

    // sampling (head-partitioned across XCDs)
    msda_sample6<<<dim3(B_ * NH * (LQ_ / QB6)), 256, 0, stream>>>(val_h, oa_h, refp, samp_bf);

    // output projection
    gemm_out<<<dim3(2, M / 128), 256, 0, stream>>>(samp_bf, Wt_out, b_out, out);
}

// Round 2
// 285.390 us; speedup vs baseline: 1.0149x; 1.0043x over previous
//
#include <hip/hip_runtime.h>
#include <hip/hip_bf16.h>
#include <hip/hip_fp16.h>
#include <type_traits>

// ---- problem constants ----
#define B_    2
#define LQ_   21760
#define LEN_  21760
#define DM    256
#define NH    8
#define NL    4
#define NP    4
#define HD    32

// workspace layout (bytes)
#define WS_VAL   0u            // f16 value [B][H][21760][32]      22,282,240
#define WS_SAMP  22282240u     // bf16 sampled [B*LQ][256]         22,282,240
#define WS_OA    44564480u     // f16 off|attn [B*LQ][384]         33,423,360
#define WS_WT    77987840u     // bf16 W^T arena: val|oa|out        458,752

typedef __attribute__((ext_vector_type(4))) float f32x4;
typedef __attribute__((ext_vector_type(8))) short bf16x8;
typedef __attribute__((ext_vector_type(4))) unsigned int u32x4;
typedef __attribute__((ext_vector_type(2))) unsigned int u32x2;

__device__ __forceinline__ unsigned short f2bf(float v) {
    __hip_bfloat16 h = __float2bfloat16(v);
    return *reinterpret_cast<unsigned short*>(&h);
}
__device__ __forceinline__ unsigned int pk2bf(float a, float b) {
    return (unsigned int)f2bf(a) | ((unsigned int)f2bf(b) << 16);
}
__device__ __forceinline__ unsigned int pk2h(float a, float b) {
    __half2 h = __floats2half2_rn(a, b);
    union { __half2 h; unsigned int u; } c; c.h = h; return c.u;
}
__device__ __forceinline__ __half2 u2h2(unsigned int u) {
    union { unsigned int u; __half2 h; } c; c.u = u; return c.h;
}

// ---------------------------------------------------------------------------
// All four weight transposes in one dispatch. W[K=256,N] f32 -> Wt[N,256] bf16.
// ---------------------------------------------------------------------------
__global__ __launch_bounds__(256) void wt_cvt_all(const float* __restrict__ Wv,
                                                  const float* __restrict__ Wo,
                                                  const float* __restrict__ Wa,
                                                  const float* __restrict__ Wu,
                                                  unsigned short* __restrict__ wt) {
    const float* Ws[4] = {Wv, Wo, Wa, Wu};
    const int Ns[4] = {256, 256, 128, 256};
    const unsigned int dof[4] = {0u, 65536u, 131072u, 163840u};
    const int m = blockIdx.z;
    const int n0 = blockIdx.x * 16, k0 = blockIdx.y * 16;
    if (n0 >= Ns[m]) return;
    __shared__ float tile[16][17];
    const int tx = threadIdx.x & 15, ty = threadIdx.x >> 4;
    tile[ty][tx] = Ws[m][(size_t)(k0 + ty) * Ns[m] + n0 + tx];
    __syncthreads();
    wt[dof[m] + (size_t)(n0 + ty) * 256 + k0 + tx] = f2bf(tile[tx][ty]);
}

// ---------------------------------------------------------------------------
// Merged pre-GEMMs (one dispatch, 2 jobs):
//  job0 (x=0..1): value = inpf @ Wt_val + b_val -> f16, PERMUTED [b][h][pix][32]
//  job1 (x=2..4): oa    = query @ Wt_oa + (b_off|b_attn) -> f16 flat [bq][384]
// 128x128 tile, BK=32, 4 waves. A is f32, converted to bf16 during staging.
// grid (5, 340).
// ---------------------------------------------------------------------------
__global__ __launch_bounds__(256) void gemm_pre(const float* __restrict__ inpf,
                                                const float* __restrict__ query,
                                                const unsigned short* __restrict__ Wt_val,
                                                const unsigned short* __restrict__ Wt_oa,
                                                const float* __restrict__ b_val,
                                                const float* __restrict__ b_off,
                                                const float* __restrict__ b_attn,
                                                unsigned short* __restrict__ val_h,
                                                unsigned short* __restrict__ oa_h) {
    __shared__ unsigned short As[128 * 32];
    __shared__ unsigned short Bs[128 * 32];
    const int t = threadIdx.x;
    const int wv = t >> 6;
    const int ln = t & 63;
    const int job = (blockIdx.x >= 2);
    const int n0 = (job ? (blockIdx.x - 2) : blockIdx.x) * 128;
    const int m0 = blockIdx.y * 128;
    const float* A = job ? query : inpf;
    const unsigned short* Bt = job ? Wt_oa : Wt_val;
    const int K = 256;
    const int wm = (wv & 1) * 64;
    const int wn = (wv >> 1) * 64;
    const int lrow = ln & 15;
    const int kq = ln >> 4;

    f32x4 acc[4][4] = {};

    for (int k0 = 0; k0 < K; k0 += 32) {
#pragma unroll
        for (int c = 0; c < 4; ++c) {
            const int i = t + c * 256;
            const int row = i >> 3;
            const int kq4 = (i & 7) * 4;
            f32x4 v = *(const f32x4*)&A[(size_t)(m0 + row) * K + k0 + kq4];
            uint2 p = make_uint2(pk2bf(v.x, v.y), pk2bf(v.z, v.w));
            *(uint2*)((char*)As + row * 64 + kq4 * 2) = p;
        }
#pragma unroll
        for (int c = 0; c < 2; ++c) {
            const int o = c * 4096 + t * 16;
            const int row = o >> 6;
            const int ke = (o & 63) >> 1;
            const unsigned short* gb = Bt + (size_t)(n0 + row) * K + k0 + ke;
            __builtin_amdgcn_global_load_lds(
                (const __attribute__((address_space(1))) void*)gb,
                (__attribute__((address_space(3))) void*)((char*)Bs + o), 16, 0, 0);
        }
        __syncthreads();

        bf16x8 af[4], bfr[4];
#pragma unroll
        for (int i = 0; i < 4; ++i) {
            af[i]  = *(const bf16x8*)((char*)As + (wm + i * 16 + lrow) * 64 + kq * 16);
            bfr[i] = *(const bf16x8*)((char*)Bs + (wn + i * 16 + lrow) * 64 + kq * 16);
        }
#pragma unroll
        for (int i = 0; i < 4; ++i)
#pragma unroll
            for (int j = 0; j < 4; ++j)
                acc[i][j] = __builtin_amdgcn_mfma_f32_16x16x32_bf16(af[i], bfr[j], acc[i][j], 0, 0, 0);
        __syncthreads();
    }

    // epilogue: C/D mapping col = lane&15, row = (lane>>4)*4 + reg
    const int b = m0 / LQ_;       // block never straddles batch (21760 % 128 == 0)
#pragma unroll
    for (int j = 0; j < 4; ++j) {
        const int n = n0 + wn + j * 16 + lrow;
        const float bb = job ? ((n < 256) ? b_off[n] : b_attn[n - 256]) : b_val[n];
#pragma unroll
        for (int i = 0; i < 4; ++i) {
            const int mrow = m0 + wm + i * 16 + kq * 4;
#pragma unroll
            for (int r = 0; r < 4; ++r) {
                const float v = acc[i][j][r] + bb;
                const unsigned short hv = (unsigned short)__half_as_ushort(__float2half(v));
                if (job) {
                    oa_h[(size_t)(mrow + r) * 384 + n] = hv;
                } else {
                    const int pix = (mrow + r) - b * LQ_;
                    const int h = n >> 5, c = n & 31;
                    val_h[((size_t)(b * NH + h) * LQ_ + pix) * HD + c] = hv;
                }
            }
        }
    }
}

// ---------------------------------------------------------------------------
// out = sampled(bf16) @ Wt_out + b_out -> f32. grid (2, 340) (x = n for LLC
// locality of the shared A-tile).
// ---------------------------------------------------------------------------
__global__ __launch_bounds__(256) void gemm_out(const unsigned short* __restrict__ Ab,
                                                const unsigned short* __restrict__ Bt,
                                                const float* __restrict__ bias,
                                                float* __restrict__ C) {
    __shared__ unsigned short As[128 * 32];
    __shared__ unsigned short Bs[128 * 32];
    const int t = threadIdx.x;
    const int wv = t >> 6;
    const int ln = t & 63;
    const int n0 = blockIdx.x * 128;
    const int m0 = blockIdx.y * 128;
    const int N = 256, K = 256;
    const int wm = (wv & 1) * 64;
    const int wn = (wv >> 1) * 64;
    const int lrow = ln & 15;
    const int kq = ln >> 4;

    f32x4 acc[4][4] = {};

    for (int k0 = 0; k0 < K; k0 += 32) {
#pragma unroll
        for (int c = 0; c < 2; ++c) {
            const int o = c * 4096 + t * 16;
            const int row = o >> 6;
            const int ke = (o & 63) >> 1;
            const unsigned short* ga = Ab + (size_t)(m0 + row) * K + k0 + ke;
            const unsigned short* gb = Bt + (size_t)(n0 + row) * K + k0 + ke;
            __builtin_amdgcn_global_load_lds(
                (const __attribute__((address_space(1))) void*)ga,
                (__attribute__((address_space(3))) void*)((char*)As + o), 16, 0, 0);
            __builtin_amdgcn_global_load_lds(
                (const __attribute__((address_space(1))) void*)gb,
                (__attribute__((address_space(3))) void*)((char*)Bs + o), 16, 0, 0);
        }
        __syncthreads();

        bf16x8 af[4], bfr[4];
#pragma unroll
        for (int i = 0; i < 4; ++i) {
            af[i]  = *(const bf16x8*)((char*)As + (wm + i * 16 + lrow) * 64 + kq * 16);
            bfr[i] = *(const bf16x8*)((char*)Bs + (wn + i * 16 + lrow) * 64 + kq * 16);
        }
#pragma unroll
        for (int i = 0; i < 4; ++i)
#pragma unroll
            for (int j = 0; j < 4; ++j)
                acc[i][j] = __builtin_amdgcn_mfma_f32_16x16x32_bf16(af[i], bfr[j], acc[i][j], 0, 0, 0);
        __syncthreads();
    }

#pragma unroll
    for (int j = 0; j < 4; ++j) {
        const int n = n0 + wn + j * 16 + lrow;
        const float bb = bias[n];
#pragma unroll
        for (int i = 0; i < 4; ++i) {
            const int mrow = m0 + wm + i * 16 + kq * 4;
#pragma unroll
            for (int r = 0; r < 4; ++r)
                C[(size_t)(mrow + r) * N + n] = acc[i][j][r] + bb;
        }
    }
}

// ---------------------------------------------------------------------------
// Deformable sampling v7: head-partitioned (v6) + DEEP SOFTWARE PIPELINE.
// Phase B latency analysis (v6 post-mortem): distance-1 prefetch left every
// wave stalled on vmcnt for ~200-300cy L2-hit gathers (VALUBusy 43%, HBM 11%,
// dur unchanged vs v5). v7: fully-unrolled lp loop with distance-6 LDS-entry
// prefetch and distance-4 value-gather prefetch -> ~8 gathers in flight/wave.
// Logical arrays, static indices only (runtime-indexed ext_vector arrays go
// to scratch).
// ---------------------------------------------------------------------------
#define QB6 32
__global__ __launch_bounds__(256) void msda_sample7(const unsigned short* __restrict__ value,
                                                    const unsigned short* __restrict__ oa,
                                                    const float* __restrict__ refp,
                                                    unsigned short* __restrict__ samp) {
    __shared__ __align__(16) char smem[9216];
    unsigned int* s_pkw = (unsigned int*)smem;            // 8 KB (phase B), aliases below
    float* s_off   = (float*)smem;                        // 32q * 32 f32 = 4 KB
    float* s_logit = (float*)(smem + 4096);               // 32q * 16 f32 = 2 KB
    float* s_aw    = (float*)(smem + 6144);               // 32q * 16 f32 = 2 KB
    float* s_ref   = (float*)(smem + 8192);               // 32q * 8 f32 = 1 KB (non-aliased)

    const int t = threadIdx.x;
    const int j = blockIdx.x;                 // 10880 blocks
    const int h = j & 7;                      // head, pinned per XCD
    const int bqc = j >> 3;                   // 0..1359
    const int b = (bqc >= 680);
    const int q0 = (bqc - b * 680) * QB6;     // batch-local query base
    const int bq0 = b * LQ_ + q0;             // global row base

    // phase 0: stage this head's oa slice (f16 -> f32) + refs, nontemporal.
    // t = q(5b) * 8 + c(3b)
    {
        const int q = t >> 3, c = t & 7;
        const unsigned short* oab = oa + (size_t)(bq0 + q) * 384;
        // 32 offsets (64 B slice at h*32, 8 B per lane)
        u32x2 r0 = __builtin_nontemporal_load((const u32x2*)(oab + h * 32) + c);
        float2 f0 = __half22float2(u2h2(r0.x));
        float2 f1 = __half22float2(u2h2(r0.y));
        f32x4 o0 = {f0.x, f0.y, f1.x, f1.y};
        ((f32x4*)s_off)[q * 8 + c] = o0;
        // 16 logits (32 B slice at 256 + h*16, 4 B per lane)
        unsigned int r1 = __builtin_nontemporal_load((const unsigned int*)(oab + 256 + h * 16) + c);
        float2 g0 = __half22float2(u2h2(r1));
        ((float2*)s_logit)[q * 8 + c] = make_float2(g0.x, g0.y);
        // 8 refs per q (32 B, 4 B per lane)
        s_ref[q * 8 + c] = __builtin_nontemporal_load(refp + (size_t)(bq0 + q) * 8 + c);
    }
    __syncthreads();

    // phase A1: 32 softmaxes (one per query, this head) over 16 logits
    if (t < 32) {
        const float* lg = s_logit + t * 16;
        float m = -1e30f;
#pragma unroll
        for (int i = 0; i < 16; ++i) m = fmaxf(m, lg[i]);
        float e[16], s = 0.f;
#pragma unroll
        for (int i = 0; i < 16; ++i) { e[i] = __expf(lg[i] - m); s += e[i]; }
        const float inv = 1.f / s;
#pragma unroll
        for (int i = 0; i < 16; ++i) s_aw[t * 16 + i] = e[i] * inv;
    }
    __syncthreads();

    // phase A2: 2 samples/thread -> registers. s = q(5b)*16 + lp(4b)
    uint4 ent[2];
    int wrd[2];
    {
        const int Wls[4] = {128, 64, 32, 16};
        const int Hls[4] = {128, 64, 32, 16};
        const int st_[4] = {0, 16384, 20480, 21504};
#pragma unroll
        for (int ii = 0; ii < 2; ++ii) {
            const int s = t * 2 + ii;
            const int q = s >> 4;
            const int lp = s & 15;
            const int l = lp >> 2;
            const int Wl = Wls[l], Hl = Hls[l], base = st_[l];
            const float ix = s_ref[q * 8 + l * 2]     * (float)Wl - 0.5f + s_off[q * 32 + lp * 2];
            const float iy = s_ref[q * 8 + l * 2 + 1] * (float)Hl - 0.5f + s_off[q * 32 + lp * 2 + 1];
            const float fix = floorf(ix), fiy = floorf(iy);
            const int x0 = (int)fix, y0 = (int)fiy;
            const float fx = ix - fix, fy = iy - fiy;
            // x-pair: start sx in [0, Wl-2]; (wl, wr) = weights of pixels sx, sx+1
            int sx; float wl, wr;
            if (x0 < 0)            { sx = 0;      wl = (x0 == -1) ? fx : 0.f;        wr = 0.f; }
            else if (x0 >= Wl - 1) { sx = Wl - 2; wl = 0.f; wr = (x0 == Wl - 1) ? (1.f - fx) : 0.f; }
            else                   { sx = x0;     wl = 1.f - fx;                     wr = fx; }
            // y rows
            const float g0 = ((y0 >= 0) & (y0 < Hl)) ? (1.f - fy) : 0.f;
            const float g1 = ((y0 + 1 >= 0) & (y0 + 1 < Hl)) ? fy : 0.f;
            const int cy0 = min(max(y0, 0), Hl - 1);
            const int cy1 = min(max(y0 + 1, 0), Hl - 1);
            const float aw = s_aw[q * 16 + lp];
            ent[ii].x = (unsigned int)(base + cy0 * Wl + sx);
            ent[ii].y = (unsigned int)(base + cy1 * Wl + sx);
            ent[ii].z = pk2h(aw * wl * g0, aw * wr * g0);
            ent[ii].w = pk2h(aw * wl * g1, aw * wr * g1);
            wrd[ii] = q * 64 + ((lp ^ (q & 7)) << 2);
        }
    }
    __syncthreads();  // phase-A reads done; safe to overwrite aliased region

#pragma unroll
    for (int ii = 0; ii < 2; ++ii)
        *(uint4*)&s_pkw[wrd[ii]] = ent[ii];
    __syncthreads();

    // phase B: wave = 8 queries x 8 dg; lane's pixel = sx + (dg>=4), ch = (dg&3)*8..
    const int lane = t & 63;
    const int wv = t >> 6;
    const int ql = lane >> 3;                 // 0..7 within wave
    const int q = wv * 8 + ql;                // block-local query 0..31
    const int dg = lane & 7;
    const char* vbase = (const char*)(value + ((size_t)(b * NH + h) * LQ_) * HD) + dg * 16;
    const unsigned int wsel = (dg < 4) ? 0x01000100u : 0x03020302u;  // v_perm: replicate lo/hi half
    const int wb = q * 64 + (ql << 2);        // swizzled entry base (bits disjoint from lp<<2)

    float facc[8] = {0.f, 0.f, 0.f, 0.f, 0.f, 0.f, 0.f, 0.f};
    __half2 ah[4] = {u2h2(0u), u2h2(0u), u2h2(0u), u2h2(0u)};

    // deep pipeline: logical arrays, ALL indices static under full unroll.
    uint4 e[16];     // LDS entries (prefetch distance 6)
    uint4 va[16];    // value row y0 (prefetch distance 4)
    uint4 vc[16];    // value row y1
#pragma unroll
    for (int i = 0; i < 6; ++i)
        e[i] = *(const uint4*)&s_pkw[wb ^ (i << 2)];
#pragma unroll
    for (int i = 0; i < 4; ++i) {
        va[i] = *(const uint4*)(vbase + (size_t)e[i].x * 64);
        vc[i] = *(const uint4*)(vbase + (size_t)e[i].y * 64);
    }

#pragma unroll
    for (int lp = 0; lp < 16; ++lp) {
        if (lp + 6 < 16)
            e[lp + 6] = *(const uint4*)&s_pkw[wb ^ ((lp + 6) << 2)];
        if (lp + 4 < 16) {
            va[lp + 4] = *(const uint4*)(vbase + (size_t)e[lp + 4].x * 64);
            vc[lp + 4] = *(const uint4*)(vbase + (size_t)e[lp + 4].y * 64);
        }
        const __half2 w0 = u2h2(__builtin_amdgcn_perm(e[lp].z, e[lp].z, wsel));
        const __half2 w1 = u2h2(__builtin_amdgcn_perm(e[lp].w, e[lp].w, wsel));
#pragma unroll
        for (int c2 = 0; c2 < 4; ++c2) {
            ah[c2] = __hfma2(w0, u2h2((&va[lp].x)[c2]), ah[c2]);
            ah[c2] = __hfma2(w1, u2h2((&vc[lp].x)[c2]), ah[c2]);
        }
        if ((lp & 3) == 3) {   // flush fp16 partials to f32 every 4 lp
#pragma unroll
            for (int c2 = 0; c2 < 4; ++c2) {
                float2 f = __half22float2(ah[c2]);
                facc[c2 * 2]     += f.x;
                facc[c2 * 2 + 1] += f.y;
                ah[c2] = u2h2(0u);
            }
        }
    }

    // combine left-pixel (dg<4) and right-pixel (dg>=4) partials
#pragma unroll
    for (int i = 0; i < 8; ++i) facc[i] += __shfl_xor(facc[i], 4);

    if (dg < 4) {
        u32x4 o;
        o.x = pk2bf(facc[0], facc[1]);
        o.y = pk2bf(facc[2], facc[3]);
        o.z = pk2bf(facc[4], facc[5]);
        o.w = pk2bf(facc[6], facc[7]);
        __builtin_nontemporal_store(o, (u32x4*)(samp + (size_t)(bq0 + q) * 256 + h * HD + dg * 8));
    }
}

extern "C" void kernel_launch(void* const* d_in, const int* in_sizes, int n_in,
                              void* d_out, int out_size, void* d_ws, size_t ws_size,
                              hipStream_t stream) {
    const float* query  = (const float*)d_in[0];
    const float* refp   = (const float*)d_in[1];
    const float* inpf   = (const float*)d_in[2];
    const float* W_off  = (const float*)d_in[3];
    const float* b_off  = (const float*)d_in[4];
    const float* W_attn = (const float*)d_in[5];
    const float* b_attn = (const float*)d_in[6];
    const float* W_val  = (const float*)d_in[7];
    const float* b_val  = (const float*)d_in[8];
    const float* W_out  = (const float*)d_in[9];
    const float* b_out  = (const float*)d_in[10];
    float* out = (float*)d_out;

    char* ws = (char*)d_ws;
    unsigned short* val_h   = (unsigned short*)(ws + WS_VAL);
    unsigned short* samp_bf = (unsigned short*)(ws + WS_SAMP);
    unsigned short* oa_h    = (unsigned short*)(ws + WS_OA);
    unsigned short* wt      = (unsigned short*)(ws + WS_WT);
    unsigned short* Wt_val  = wt;
    unsigned short* Wt_oa   = wt + 65536;
    unsigned short* Wt_out  = wt + 163840;

    const int M = B_ * LQ_;          // 43520

    wt_cvt_all<<<dim3(16, 16, 4), 256, 0, stream>>>(W_val, W_off, W_attn, W_out, wt);

    // merged value + off/attn GEMMs
    gemm_pre<<<dim3(5, M / 128), 256, 0, stream>>>(
        inpf, query, Wt_val, Wt_oa, b_val, b_off, b_attn, val_h, oa_h);

    // sampling (head-partitioned across XCDs, deep-pipelined gathers)
    msda_sample7<<<dim3(B_ * NH * (LQ_ / QB6)), 256, 0, stream>>>(val_h, oa_h, refp, samp_bf);

    // output projection
    gemm_out<<<dim3(2, M / 128), 256, 0, stream>>>(samp_bf, Wt_out, b_out, out);
}

// Round 3
// 279.553 us; speedup vs baseline: 1.0361x; 1.0209x over previous
//
#include <hip/hip_runtime.h>
#include <hip/hip_bf16.h>
#include <hip/hip_fp16.h>
#include <type_traits>

// ---- problem constants ----
#define B_    2
#define LQ_   21760
#define LEN_  21760
#define DM    256
#define NH    8
#define NL    4
#define NP    4
#define HD    32

// workspace layout (bytes)
#define WS_VAL   0u            // f16 value [B][H][21760][32]      22,282,240
#define WS_SAMP  22282240u     // bf16 sampled [B*LQ][256]         22,282,240
#define WS_OA    44564480u     // f16 off|attn [B*LQ][384]         33,423,360
#define WS_WT    77987840u     // bf16 W^T arena: val|oa|out        458,752

typedef __attribute__((ext_vector_type(4))) float f32x4;
typedef __attribute__((ext_vector_type(8))) short bf16x8;
typedef __attribute__((ext_vector_type(4))) unsigned int u32x4;
typedef __attribute__((ext_vector_type(2))) unsigned int u32x2;

__device__ __forceinline__ unsigned short f2bf(float v) {
    __hip_bfloat16 h = __float2bfloat16(v);
    return *reinterpret_cast<unsigned short*>(&h);
}
__device__ __forceinline__ unsigned int pk2bf(float a, float b) {
    return (unsigned int)f2bf(a) | ((unsigned int)f2bf(b) << 16);
}
__device__ __forceinline__ unsigned int pk2h(float a, float b) {
    __half2 h = __floats2half2_rn(a, b);
    union { __half2 h; unsigned int u; } c; c.h = h; return c.u;
}
__device__ __forceinline__ __half2 u2h2(unsigned int u) {
    union { unsigned int u; __half2 h; } c; c.u = u; return c.h;
}

// forced 16-B gather: named register quad, cannot be re-rolled by the scheduler
__device__ __forceinline__ void gload16(u32x4& d, const char* p) {
    asm volatile("global_load_dwordx4 %0, %1, off" : "=v"(d) : "v"(p));
}

// ---------------------------------------------------------------------------
// All four weight transposes in one dispatch. W[K=256,N] f32 -> Wt[N,256] bf16.
// ---------------------------------------------------------------------------
__global__ __launch_bounds__(256) void wt_cvt_all(const float* __restrict__ Wv,
                                                  const float* __restrict__ Wo,
                                                  const float* __restrict__ Wa,
                                                  const float* __restrict__ Wu,
                                                  unsigned short* __restrict__ wt) {
    const float* Ws[4] = {Wv, Wo, Wa, Wu};
    const int Ns[4] = {256, 256, 128, 256};
    const unsigned int dof[4] = {0u, 65536u, 131072u, 163840u};
    const int m = blockIdx.z;
    const int n0 = blockIdx.x * 16, k0 = blockIdx.y * 16;
    if (n0 >= Ns[m]) return;
    __shared__ float tile[16][17];
    const int tx = threadIdx.x & 15, ty = threadIdx.x >> 4;
    tile[ty][tx] = Ws[m][(size_t)(k0 + ty) * Ns[m] + n0 + tx];
    __syncthreads();
    wt[dof[m] + (size_t)(n0 + ty) * 256 + k0 + tx] = f2bf(tile[tx][ty]);
}

// ---------------------------------------------------------------------------
// Merged pre-GEMMs (one dispatch, 2 jobs):
//  job0 (x=0..1): value = inpf @ Wt_val + b_val -> f16, PERMUTED [b][h][pix][32]
//  job1 (x=2..4): oa    = query @ Wt_oa + (b_off|b_attn) -> f16 flat [bq][384]
// 128x128 tile, BK=32, 4 waves. A is f32, converted to bf16 during staging.
// grid (5, 340).
// ---------------------------------------------------------------------------
__global__ __launch_bounds__(256) void gemm_pre(const float* __restrict__ inpf,
                                                const float* __restrict__ query,
                                                const unsigned short* __restrict__ Wt_val,
                                                const unsigned short* __restrict__ Wt_oa,
                                                const float* __restrict__ b_val,
                                                const float* __restrict__ b_off,
                                                const float* __restrict__ b_attn,
                                                unsigned short* __restrict__ val_h,
                                                unsigned short* __restrict__ oa_h) {
    __shared__ unsigned short As[128 * 32];
    __shared__ unsigned short Bs[128 * 32];
    const int t = threadIdx.x;
    const int wv = t >> 6;
    const int ln = t & 63;
    const int job = (blockIdx.x >= 2);
    const int n0 = (job ? (blockIdx.x - 2) : blockIdx.x) * 128;
    const int m0 = blockIdx.y * 128;
    const float* A = job ? query : inpf;
    const unsigned short* Bt = job ? Wt_oa : Wt_val;
    const int K = 256;
    const int wm = (wv & 1) * 64;
    const int wn = (wv >> 1) * 64;
    const int lrow = ln & 15;
    const int kq = ln >> 4;

    f32x4 acc[4][4] = {};

    for (int k0 = 0; k0 < K; k0 += 32) {
#pragma unroll
        for (int c = 0; c < 4; ++c) {
            const int i = t + c * 256;
            const int row = i >> 3;
            const int kq4 = (i & 7) * 4;
            f32x4 v = *(const f32x4*)&A[(size_t)(m0 + row) * K + k0 + kq4];
            uint2 p = make_uint2(pk2bf(v.x, v.y), pk2bf(v.z, v.w));
            *(uint2*)((char*)As + row * 64 + kq4 * 2) = p;
        }
#pragma unroll
        for (int c = 0; c < 2; ++c) {
            const int o = c * 4096 + t * 16;
            const int row = o >> 6;
            const int ke = (o & 63) >> 1;
            const unsigned short* gb = Bt + (size_t)(n0 + row) * K + k0 + ke;
            __builtin_amdgcn_global_load_lds(
                (const __attribute__((address_space(1))) void*)gb,
                (__attribute__((address_space(3))) void*)((char*)Bs + o), 16, 0, 0);
        }
        __syncthreads();

        bf16x8 af[4], bfr[4];
#pragma unroll
        for (int i = 0; i < 4; ++i) {
            af[i]  = *(const bf16x8*)((char*)As + (wm + i * 16 + lrow) * 64 + kq * 16);
            bfr[i] = *(const bf16x8*)((char*)Bs + (wn + i * 16 + lrow) * 64 + kq * 16);
        }
#pragma unroll
        for (int i = 0; i < 4; ++i)
#pragma unroll
            for (int j = 0; j < 4; ++j)
                acc[i][j] = __builtin_amdgcn_mfma_f32_16x16x32_bf16(af[i], bfr[j], acc[i][j], 0, 0, 0);
        __syncthreads();
    }

    // epilogue: C/D mapping col = lane&15, row = (lane>>4)*4 + reg
    const int b = m0 / LQ_;       // block never straddles batch (21760 % 128 == 0)
#pragma unroll
    for (int j = 0; j < 4; ++j) {
        const int n = n0 + wn + j * 16 + lrow;
        const float bb = job ? ((n < 256) ? b_off[n] : b_attn[n - 256]) : b_val[n];
#pragma unroll
        for (int i = 0; i < 4; ++i) {
            const int mrow = m0 + wm + i * 16 + kq * 4;
#pragma unroll
            for (int r = 0; r < 4; ++r) {
                const float v = acc[i][j][r] + bb;
                const unsigned short hv = (unsigned short)__half_as_ushort(__float2half(v));
                if (job) {
                    oa_h[(size_t)(mrow + r) * 384 + n] = hv;
                } else {
                    const int pix = (mrow + r) - b * LQ_;
                    const int h = n >> 5, c = n & 31;
                    val_h[((size_t)(b * NH + h) * LQ_ + pix) * HD + c] = hv;
                }
            }
        }
    }
}

// ---------------------------------------------------------------------------
// out = sampled(bf16) @ Wt_out + b_out -> f32. grid (2, 340).
// ---------------------------------------------------------------------------
__global__ __launch_bounds__(256) void gemm_out(const unsigned short* __restrict__ Ab,
                                                const unsigned short* __restrict__ Bt,
                                                const float* __restrict__ bias,
                                                float* __restrict__ C) {
    __shared__ unsigned short As[128 * 32];
    __shared__ unsigned short Bs[128 * 32];
    const int t = threadIdx.x;
    const int wv = t >> 6;
    const int ln = t & 63;
    const int n0 = blockIdx.x * 128;
    const int m0 = blockIdx.y * 128;
    const int N = 256, K = 256;
    const int wm = (wv & 1) * 64;
    const int wn = (wv >> 1) * 64;
    const int lrow = ln & 15;
    const int kq = ln >> 4;

    f32x4 acc[4][4] = {};

    for (int k0 = 0; k0 < K; k0 += 32) {
#pragma unroll
        for (int c = 0; c < 2; ++c) {
            const int o = c * 4096 + t * 16;
            const int row = o >> 6;
            const int ke = (o & 63) >> 1;
            const unsigned short* ga = Ab + (size_t)(m0 + row) * K + k0 + ke;
            const unsigned short* gb = Bt + (size_t)(n0 + row) * K + k0 + ke;
            __builtin_amdgcn_global_load_lds(
                (const __attribute__((address_space(1))) void*)ga,
                (__attribute__((address_space(3))) void*)((char*)As + o), 16, 0, 0);
            __builtin_amdgcn_global_load_lds(
                (const __attribute__((address_space(1))) void*)gb,
                (__attribute__((address_space(3))) void*)((char*)Bs + o), 16, 0, 0);
        }
        __syncthreads();

        bf16x8 af[4], bfr[4];
#pragma unroll
        for (int i = 0; i < 4; ++i) {
            af[i]  = *(const bf16x8*)((char*)As + (wm + i * 16 + lrow) * 64 + kq * 16);
            bfr[i] = *(const bf16x8*)((char*)Bs + (wn + i * 16 + lrow) * 64 + kq * 16);
        }
#pragma unroll
        for (int i = 0; i < 4; ++i)
#pragma unroll
            for (int j = 0; j < 4; ++j)
                acc[i][j] = __builtin_amdgcn_mfma_f32_16x16x32_bf16(af[i], bfr[j], acc[i][j], 0, 0, 0);
        __syncthreads();
    }

#pragma unroll
    for (int j = 0; j < 4; ++j) {
        const int n = n0 + wn + j * 16 + lrow;
        const float bb = bias[n];
#pragma unroll
        for (int i = 0; i < 4; ++i) {
            const int mrow = m0 + wm + i * 16 + kq * 4;
#pragma unroll
            for (int r = 0; r < 4; ++r)
                C[(size_t)(mrow + r) * N + n] = acc[i][j][r] + bb;
        }
    }
}

// ---------------------------------------------------------------------------
// Deformable sampling v8: head-partitioned (v6) + FORCED deep pipeline.
// v7 post-mortem: plain-C++ distance-4 prefetch was re-rolled by the
// scheduler (VGPR stayed 32, dur unchanged). v8 forces it at ISA level:
// inline-asm global_load_dwordx4 into named register quads + counted
// s_waitcnt vmcnt(N) + sched_barrier(0) (T3/T4 recipe, rule #18).
// Steady state: 16 gathers in flight/wave; consume group of 4 lp while
// 8-16 loads outstanding. Weights re-read from LDS at consume time so only
// data quads stay live (~130 VGPR, 4 waves/SIMD).
// vmcnt counts are exact: phase B has no other vmem ops (compiler loads all
// drained in phase 0 before the barrier; store happens after vmcnt(0)).
// ---------------------------------------------------------------------------
#define QB6 32

#define MSDA_VMWAIT(n) { asm volatile("s_waitcnt vmcnt(" #n ")" ::: "memory"); \
                         __builtin_amdgcn_sched_barrier(0); }

#define MSDA_ISSUE(i) u32x4 va_##i, vc_##i; { \
    const u32x2 xy = *(const u32x2*)&s_pkw[wb ^ ((i) << 2)]; \
    gload16(va_##i, vbase + (size_t)xy[0] * 64); \
    gload16(vc_##i, vbase + (size_t)xy[1] * 64); }

#define MSDA_CONSUME(i) { \
    const u32x2 zw = *(const u32x2*)&s_pkw[(wb ^ ((i) << 2)) + 2]; \
    const __half2 w0 = u2h2(__builtin_amdgcn_perm(zw[0], zw[0], wsel)); \
    const __half2 w1 = u2h2(__builtin_amdgcn_perm(zw[1], zw[1], wsel)); \
    ah0 = __hfma2(w0, u2h2(va_##i[0]), ah0); \
    ah1 = __hfma2(w0, u2h2(va_##i[1]), ah1); \
    ah2 = __hfma2(w0, u2h2(va_##i[2]), ah2); \
    ah3 = __hfma2(w0, u2h2(va_##i[3]), ah3); \
    ah0 = __hfma2(w1, u2h2(vc_##i[0]), ah0); \
    ah1 = __hfma2(w1, u2h2(vc_##i[1]), ah1); \
    ah2 = __hfma2(w1, u2h2(vc_##i[2]), ah2); \
    ah3 = __hfma2(w1, u2h2(vc_##i[3]), ah3); }

#define MSDA_FLUSH() { \
    float2 f0 = __half22float2(ah0); facc0 += f0.x; facc1 += f0.y; ah0 = u2h2(0u); \
    float2 f1 = __half22float2(ah1); facc2 += f1.x; facc3 += f1.y; ah1 = u2h2(0u); \
    float2 f2 = __half22float2(ah2); facc4 += f2.x; facc5 += f2.y; ah2 = u2h2(0u); \
    float2 f3 = __half22float2(ah3); facc6 += f3.x; facc7 += f3.y; ah3 = u2h2(0u); }

__global__ __launch_bounds__(256) void msda_sample8(const unsigned short* __restrict__ value,
                                                    const unsigned short* __restrict__ oa,
                                                    const float* __restrict__ refp,
                                                    unsigned short* __restrict__ samp) {
    __shared__ __align__(16) char smem[9216];
    unsigned int* s_pkw = (unsigned int*)smem;            // 8 KB (phase B), aliases below
    float* s_off   = (float*)smem;                        // 32q * 32 f32 = 4 KB
    float* s_logit = (float*)(smem + 4096);               // 32q * 16 f32 = 2 KB
    float* s_aw    = (float*)(smem + 6144);               // 32q * 16 f32 = 2 KB
    float* s_ref   = (float*)(smem + 8192);               // 32q * 8 f32 = 1 KB (non-aliased)

    const int t = threadIdx.x;
    const int j = blockIdx.x;                 // 10880 blocks
    const int h = j & 7;                      // head, pinned per XCD
    const int bqc = j >> 3;                   // 0..1359
    const int b = (bqc >= 680);
    const int q0 = (bqc - b * 680) * QB6;     // batch-local query base
    const int bq0 = b * LQ_ + q0;             // global row base

    // phase 0: stage this head's oa slice (f16 -> f32) + refs, nontemporal.
    {
        const int q = t >> 3, c = t & 7;
        const unsigned short* oab = oa + (size_t)(bq0 + q) * 384;
        u32x2 r0 = __builtin_nontemporal_load((const u32x2*)(oab + h * 32) + c);
        float2 f0 = __half22float2(u2h2(r0.x));
        float2 f1 = __half22float2(u2h2(r0.y));
        f32x4 o0 = {f0.x, f0.y, f1.x, f1.y};
        ((f32x4*)s_off)[q * 8 + c] = o0;
        unsigned int r1 = __builtin_nontemporal_load((const unsigned int*)(oab + 256 + h * 16) + c);
        float2 g0 = __half22float2(u2h2(r1));
        ((float2*)s_logit)[q * 8 + c] = make_float2(g0.x, g0.y);
        s_ref[q * 8 + c] = __builtin_nontemporal_load(refp + (size_t)(bq0 + q) * 8 + c);
    }
    __syncthreads();

    // phase A1: 32 softmaxes (one per query, this head) over 16 logits
    if (t < 32) {
        const float* lg = s_logit + t * 16;
        float m = -1e30f;
#pragma unroll
        for (int i = 0; i < 16; ++i) m = fmaxf(m, lg[i]);
        float e[16], s = 0.f;
#pragma unroll
        for (int i = 0; i < 16; ++i) { e[i] = __expf(lg[i] - m); s += e[i]; }
        const float inv = 1.f / s;
#pragma unroll
        for (int i = 0; i < 16; ++i) s_aw[t * 16 + i] = e[i] * inv;
    }
    __syncthreads();

    // phase A2: 2 samples/thread -> registers. s = q(5b)*16 + lp(4b)
    uint4 ent[2];
    int wrd[2];
    {
        const int Wls[4] = {128, 64, 32, 16};
        const int Hls[4] = {128, 64, 32, 16};
        const int st_[4] = {0, 16384, 20480, 21504};
#pragma unroll
        for (int ii = 0; ii < 2; ++ii) {
            const int s = t * 2 + ii;
            const int q = s >> 4;
            const int lp = s & 15;
            const int l = lp >> 2;
            const int Wl = Wls[l], Hl = Hls[l], base = st_[l];
            const float ix = s_ref[q * 8 + l * 2]     * (float)Wl - 0.5f + s_off[q * 32 + lp * 2];
            const float iy = s_ref[q * 8 + l * 2 + 1] * (float)Hl - 0.5f + s_off[q * 32 + lp * 2 + 1];
            const float fix = floorf(ix), fiy = floorf(iy);
            const int x0 = (int)fix, y0 = (int)fiy;
            const float fx = ix - fix, fy = iy - fiy;
            int sx; float wl, wr;
            if (x0 < 0)            { sx = 0;      wl = (x0 == -1) ? fx : 0.f;        wr = 0.f; }
            else if (x0 >= Wl - 1) { sx = Wl - 2; wl = 0.f; wr = (x0 == Wl - 1) ? (1.f - fx) : 0.f; }
            else                   { sx = x0;     wl = 1.f - fx;                     wr = fx; }
            const float g0 = ((y0 >= 0) & (y0 < Hl)) ? (1.f - fy) : 0.f;
            const float g1 = ((y0 + 1 >= 0) & (y0 + 1 < Hl)) ? fy : 0.f;
            const int cy0 = min(max(y0, 0), Hl - 1);
            const int cy1 = min(max(y0 + 1, 0), Hl - 1);
            const float aw = s_aw[q * 16 + lp];
            ent[ii].x = (unsigned int)(base + cy0 * Wl + sx);
            ent[ii].y = (unsigned int)(base + cy1 * Wl + sx);
            ent[ii].z = pk2h(aw * wl * g0, aw * wr * g0);
            ent[ii].w = pk2h(aw * wl * g1, aw * wr * g1);
            wrd[ii] = q * 64 + ((lp ^ (q & 7)) << 2);
        }
    }
    __syncthreads();  // phase-A reads done; safe to overwrite aliased region

#pragma unroll
    for (int ii = 0; ii < 2; ++ii)
        *(uint4*)&s_pkw[wrd[ii]] = ent[ii];
    __syncthreads();

    // phase B: wave = 8 queries x 8 dg; lane's pixel = sx + (dg>=4), ch = (dg&3)*8..
    const int lane = t & 63;
    const int wv = t >> 6;
    const int ql = lane >> 3;                 // 0..7 within wave
    const int q = wv * 8 + ql;                // block-local query 0..31
    const int dg = lane & 7;
    const char* vbase = (const char*)(value + ((size_t)(b * NH + h) * LQ_) * HD) + dg * 16;
    const unsigned int wsel = (dg < 4) ? 0x01000100u : 0x03020302u;  // v_perm: replicate lo/hi half
    const int wb = q * 64 + (ql << 2);        // swizzled entry base (bits disjoint from lp<<2)

    float facc0 = 0.f, facc1 = 0.f, facc2 = 0.f, facc3 = 0.f;
    float facc4 = 0.f, facc5 = 0.f, facc6 = 0.f, facc7 = 0.f;
    __half2 ah0 = u2h2(0u), ah1 = u2h2(0u), ah2 = u2h2(0u), ah3 = u2h2(0u);

    // --- forced pipeline: 16 loads in flight steady-state ---
    MSDA_ISSUE(0)  MSDA_ISSUE(1)  MSDA_ISSUE(2)  MSDA_ISSUE(3)
    MSDA_ISSUE(4)  MSDA_ISSUE(5)  MSDA_ISSUE(6)  MSDA_ISSUE(7)
    MSDA_VMWAIT(8)                    // lp 0..3 complete; 4..7 outstanding
    MSDA_ISSUE(8)  MSDA_ISSUE(9)  MSDA_ISSUE(10) MSDA_ISSUE(11)
    MSDA_CONSUME(0) MSDA_CONSUME(1) MSDA_CONSUME(2) MSDA_CONSUME(3)
    MSDA_FLUSH()
    MSDA_VMWAIT(8)                    // lp 4..7 complete; 8..11 outstanding
    MSDA_ISSUE(12) MSDA_ISSUE(13) MSDA_ISSUE(14) MSDA_ISSUE(15)
    MSDA_CONSUME(4) MSDA_CONSUME(5) MSDA_CONSUME(6) MSDA_CONSUME(7)
    MSDA_FLUSH()
    MSDA_VMWAIT(8)                    // lp 8..11 complete; 12..15 outstanding
    MSDA_CONSUME(8) MSDA_CONSUME(9) MSDA_CONSUME(10) MSDA_CONSUME(11)
    MSDA_FLUSH()
    MSDA_VMWAIT(0)                    // all done
    MSDA_CONSUME(12) MSDA_CONSUME(13) MSDA_CONSUME(14) MSDA_CONSUME(15)
    MSDA_FLUSH()

    // combine left-pixel (dg<4) and right-pixel (dg>=4) partials
    facc0 += __shfl_xor(facc0, 4);
    facc1 += __shfl_xor(facc1, 4);
    facc2 += __shfl_xor(facc2, 4);
    facc3 += __shfl_xor(facc3, 4);
    facc4 += __shfl_xor(facc4, 4);
    facc5 += __shfl_xor(facc5, 4);
    facc6 += __shfl_xor(facc6, 4);
    facc7 += __shfl_xor(facc7, 4);

    if (dg < 4) {
        u32x4 o;
        o.x = pk2bf(facc0, facc1);
        o.y = pk2bf(facc2, facc3);
        o.z = pk2bf(facc4, facc5);
        o.w = pk2bf(facc6, facc7);
        __builtin_nontemporal_store(o, (u32x4*)(samp + (size_t)(bq0 + q) * 256 + h * HD + dg * 8));
    }
}

extern "C" void kernel_launch(void* const* d_in, const int* in_sizes, int n_in,
                              void* d_out, int out_size, void* d_ws, size_t ws_size,
                              hipStream_t stream) {
    const float* query  = (const float*)d_in[0];
    const float* refp   = (const float*)d_in[1];
    const float* inpf   = (const float*)d_in[2];
    const float* W_off  = (const float*)d_in[3];
    const float* b_off  = (const float*)d_in[4];
    const float* W_attn = (const float*)d_in[5];
    const float* b_attn = (const float*)d_in[6];
    const float* W_val  = (const float*)d_in[7];
    const float* b_val  = (const float*)d_in[8];
    const float* W_out  = (const float*)d_in[9];
    const float* b_out  = (const float*)d_in[10];
    float* out = (float*)d_out;

    char* ws = (char*)d_ws;
    unsigned short* val_h   = (unsigned short*)(ws + WS_VAL);
    unsigned short* samp_bf = (unsigned short*)(ws + WS_SAMP);
    unsigned short* oa_h    = (unsigned short*)(ws + WS_OA);
    unsigned short* wt      = (unsigned short*)(ws + WS_WT);
    unsigned short* Wt_val  = wt;
    unsigned short* Wt_oa   = wt + 65536;
    unsigned short* Wt_out  = wt + 163840;

    const int M = B_ * LQ_;          // 43520

    wt_cvt_all<<<dim3(16, 16, 4), 256, 0, stream>>>(W_val, W_off, W_attn, W_out, wt);

    // merged value + off/attn GEMMs
    gemm_pre<<<dim3(5, M / 128), 256, 0, stream>>>(
        inpf, query, Wt_val, Wt_oa, b_val, b_off, b_attn, val_h, oa_h);

    // sampling (head-partitioned, ISA-forced 16-deep gather pipeline)
    msda_sample8<<<dim3(B_ * NH * (LQ_ / QB6)), 256, 0, stream>>>(val_h, oa_h, refp, samp_bf);

    // output projection
    gemm_out<<<dim3(2, M / 128), 256, 0, stream>>>(samp_bf, Wt_out, b_out, out);
}